// Round 5
// baseline (858.226 us; speedup 1.0000x reference)
//
#include <hip/hip_runtime.h>
#include <hip/hip_bf16.h>
#include <math.h>

// Problem constants
#define Bq 128
#define Nq 100
#define Dq 2048
#define Hq 1024
#define Oq 1600
#define Aq 400
#define Lq 2048
#define Mq (Bq * Nq)     // 12800 rows max
#define OqP 1664         // Oq padded to multiple of 128
#define AqP 512          // Aq padded to multiple of 128

typedef __attribute__((ext_vector_type(8))) short bf16x8;
typedef __attribute__((ext_vector_type(4))) float f32x4;
typedef unsigned short ushort;

// ---------------- helpers ----------------
__device__ __forceinline__ void split1(float v, ushort& h, ushort& l) {
    __hip_bfloat16 bh = __float2bfloat16(v);          // RNE
    float fh = __bfloat162float(bh);
    __hip_bfloat16 bl = __float2bfloat16(v - fh);     // exact residual, then RNE
    h = __builtin_bit_cast(ushort, bh);
    l = __builtin_bit_cast(ushort, bl);
}

__device__ __forceinline__ void gl_lds16(const ushort* g, ushort* lds) {
    __builtin_amdgcn_global_load_lds(
        (const __attribute__((address_space(1))) unsigned int*)g,
        (__attribute__((address_space(3))) unsigned int*)lds,
        16, 0, 0);
}

// ------------- row compaction: offsets + rowmap -------------
__global__ void build_offsets(const int* __restrict__ num_descs,
                              int* __restrict__ off, int* __restrict__ mc,
                              int* __restrict__ rowmap)
{
    __shared__ int cnt[Bq];
    __shared__ int offs[Bq + 1];
    const int t = threadIdx.x;            // 0..127
    int nd = num_descs[t];
    nd = nd < 0 ? 0 : (nd > Nq ? Nq : nd);
    const int c = nd < 1 ? 1 : nd;
    cnt[t] = c;
    __syncthreads();
    if (t == 0) {
        int s = 0;
        for (int i = 0; i < Bq; i++) { offs[i] = s; s += cnt[i]; }
        offs[Bq] = s;
        mc[0] = s;                          // Mc
        mc[1] = (s + 127) & ~127;           // McPad
    }
    __syncthreads();
    off[t] = offs[t];
    for (int i = t; i < Mq; i += Bq) rowmap[i] = -1;
    __syncthreads();
    const int o = offs[t];
    for (int n = 0; n < c; n++) rowmap[o + n] = t * Nq + n;
}

// ---------------- gather + split x into compact hi/lo bf16 ----------------
__global__ void split_compact(const float* __restrict__ x,
                              const int* __restrict__ rowmap,
                              const int* __restrict__ mc,
                              ushort* __restrict__ hi, ushort* __restrict__ lo)
{
    const long i = ((long)blockIdx.x * blockDim.x + threadIdx.x) * 8;
    const int c = (int)(i >> 11);          // compact row (Dq=2048)
    if (c >= mc[1]) return;
    const int orig = (c < mc[0]) ? rowmap[c] : -1;
    ushort h[8], l[8];
    if (orig < 0) {
#pragma unroll
        for (int j = 0; j < 8; j++) { h[j] = 0; l[j] = 0; }
    } else {
        const float* src = x + (size_t)orig * Dq + (i & 2047);
        float4 v0 = *(const float4*)(src);
        float4 v1 = *(const float4*)(src + 4);
        float v[8] = {v0.x, v0.y, v0.z, v0.w, v1.x, v1.y, v1.z, v1.w};
#pragma unroll
        for (int j = 0; j < 8; j++) split1(v[j], h[j], l[j]);
    }
    *(bf16x8*)(hi + i) = *(bf16x8*)h;
    *(bf16x8*)(lo + i) = *(bf16x8*)l;
}

// ------- batched transpose+split: W[K][N] -> Wt_hi/lo[Npad][K], 6 segments -------
struct TSeg { const float* W; ushort* Th; ushort* Tl; int K; int N; int gx; int base; };
struct TSegs { TSeg s[6]; };

__global__ void tsplit_all(TSegs a)
{
    const int id = blockIdx.x;
    TSeg sg = a.s[5];
#pragma unroll
    for (int i = 4; i >= 0; i--) if (id < a.s[i + 1].base) sg = a.s[i];
    const int local = id - sg.base;
    const int bn = (local % sg.gx) * 32;
    const int bk = (local / sg.gx) * 32;

    __shared__ float t[32][33];
    const int tx = threadIdx.x & 31, ty = threadIdx.x >> 5;   // ty 0..7
#pragma unroll
    for (int i = 0; i < 4; i++) {
        const int k = bk + ty + i * 8, n = bn + tx;
        t[ty + i * 8][tx] = (n < sg.N) ? sg.W[(size_t)k * sg.N + n] : 0.f;
    }
    __syncthreads();
#pragma unroll
    for (int i = 0; i < 4; i++) {
        const int n = bn + ty + i * 8, k = bk + tx;
        const float v = t[tx][ty + i * 8];
        ushort h, l;
        split1(v, h, l);
        sg.Th[(size_t)n * sg.K + k] = h;
        sg.Tl[(size_t)n * sg.K + k] = l;
    }
}

// ---------------- split-bf16 MFMA GEMM (16x16x32, B via LDS, A direct) ----------------
struct GArgs {
    const ushort* Ah; const ushort* Al;     // A [McPad][lda] split
    const ushort* Bh; const ushort* Bl;     // B [Npad][K] split (transposed)
    const float* bias;
    float* Cf; ushort* Ch; ushort* Cl;      // outputs
    int K, Npad, Nreal, lda, ldc, mode;     // mode 1: relu+split write; 0: fp32 write
};

__global__ __launch_bounds__(256) void gemm_split(GArgs g0, GArgs g1,
                                                  const int* __restrict__ mcp)
{
    const GArgs g = (blockIdx.z == 0) ? g0 : g1;
    const int bm = blockIdx.y * 128;
    const int bn = blockIdx.x * 128;
    if (bn >= g.Npad) return;
    if (bm >= mcp[1]) return;

    __shared__ __align__(16) ushort sBh[128 * 32];
    __shared__ __align__(16) ushort sBl[128 * 32];

    const int tid  = threadIdx.x;
    const int wave = tid >> 6;           // 0..3
    const int lane = tid & 63;
    const int wm = (wave >> 1) * 64;     // wave's 64x64 quadrant
    const int wn = (wave & 1) * 64;
    const int lm   = lane & 15;
    const int quad = lane >> 4;          // 0..3

    // B staging (DMA): per wave 2 instrs per buffer; covers rows wave*32 + [0..31]
    const int srow = wave * 32 + (lane >> 2);       // 0..127 (q=0 half)
    const int scol = (lane & 3) * 8;                // k element offset
    const ushort* gBh = g.Bh + (size_t)(bn + srow) * g.K + scol;
    const ushort* gBl = g.Bl + (size_t)(bn + srow) * g.K + scol;
    const size_t rstepB = (size_t)16 * g.K;
    ushort* lBh0 = &sBh[(wave * 32) * 32];  ushort* lBh1 = &sBh[(wave * 32 + 16) * 32];
    ushort* lBl0 = &sBl[(wave * 32) * 32];  ushort* lBl1 = &sBl[(wave * 32 + 16) * 32];

    // A direct-global fragment pointers: 4 i-tiles x hi/lo, lane reads 8 contiguous bf16
    const ushort* gAh[4];
    const ushort* gAl[4];
#pragma unroll
    for (int i = 0; i < 4; i++) {
        const int row = bm + wm + i * 16 + lm;
        gAh[i] = g.Ah + (size_t)row * g.lda + quad * 8;
        gAl[i] = g.Al + (size_t)row * g.lda + quad * 8;
    }

    int boff[4];
#pragma unroll
    for (int i = 0; i < 4; i++) boff[i] = (wn + i * 16 + lm) * 32 + quad * 8;

    f32x4 acc[4][4] = {};

    for (int k0 = 0; k0 < g.K; k0 += 32) {
        // issue B DMA + A global loads; both drained by the pre-barrier vmcnt(0)
        gl_lds16(gBh + k0, lBh0);  gl_lds16(gBh + rstepB + k0, lBh1);
        gl_lds16(gBl + k0, lBl0);  gl_lds16(gBl + rstepB + k0, lBl1);

        bf16x8 ah[4], al[4];
#pragma unroll
        for (int i = 0; i < 4; i++) {
            ah[i] = *(const bf16x8*)(gAh[i] + k0);
            al[i] = *(const bf16x8*)(gAl[i] + k0);
        }
        __syncthreads();

        bf16x8 bh[4], bl[4];
#pragma unroll
        for (int i = 0; i < 4; i++) {
            bh[i] = *(const bf16x8*)&sBh[boff[i]];
            bl[i] = *(const bf16x8*)&sBl[boff[i]];
        }
#pragma unroll
        for (int i = 0; i < 4; i++)
#pragma unroll
            for (int j = 0; j < 4; j++) {
                acc[i][j] = __builtin_amdgcn_mfma_f32_16x16x32_bf16(ah[i], bh[j], acc[i][j], 0, 0, 0);
                acc[i][j] = __builtin_amdgcn_mfma_f32_16x16x32_bf16(ah[i], bl[j], acc[i][j], 0, 0, 0);
                acc[i][j] = __builtin_amdgcn_mfma_f32_16x16x32_bf16(al[i], bh[j], acc[i][j], 0, 0, 0);
            }
        __syncthreads();
    }

    // epilogue: C/D layout col=lane&15, row=quad*4+reg (verified)
#pragma unroll
    for (int j = 0; j < 4; j++) {
        const int col = bn + wn + j * 16 + lm;
        if (col < g.Nreal) {
            const float bv = g.bias[col];
#pragma unroll
            for (int i = 0; i < 4; i++) {
#pragma unroll
                for (int r = 0; r < 4; r++) {
                    const int row = bm + wm + i * 16 + quad * 4 + r;
                    float v = acc[i][j][r] + bv;
                    if (g.mode == 1) {
                        v = fmaxf(v, 0.f);
                        ushort h, l;
                        split1(v, h, l);
                        g.Ch[(size_t)row * g.ldc + col] = h;
                        g.Cl[(size_t)row * g.ldc + col] = l;
                    } else {
                        g.Cf[(size_t)row * g.ldc + col] = v;
                    }
                }
            }
        }
    }
}

// ------------- fused per-row softmax stats for both branches -------------
__global__ void softmax_stats2(const float* __restrict__ Zo, const float* __restrict__ Za,
                               const int* __restrict__ mc,
                               float* __restrict__ mxo, float* __restrict__ smo,
                               float* __restrict__ mxa, float* __restrict__ sma)
{
    const int r = blockIdx.x;
    if (r >= mc[0]) return;
    const float* Z; int ncols; float* mx; float* sm;
    if (blockIdx.y == 0) { Z = Zo; ncols = Oq; mx = mxo; sm = smo; }
    else                 { Z = Za; ncols = Aq; mx = mxa; sm = sma; }
    const float* row = Z + (size_t)r * ncols;
    __shared__ float red[256];
    float m = -INFINITY;
    for (int c = threadIdx.x; c < ncols; c += 256) m = fmaxf(m, row[c]);
    red[threadIdx.x] = m;
    __syncthreads();
    for (int s = 128; s > 0; s >>= 1) {
        if (threadIdx.x < s) red[threadIdx.x] = fmaxf(red[threadIdx.x], red[threadIdx.x + s]);
        __syncthreads();
    }
    m = red[0];
    __syncthreads();
    float su = 0.f;
    for (int c = threadIdx.x; c < ncols; c += 256) su += expf(row[c] - m);
    red[threadIdx.x] = su;
    __syncthreads();
    for (int s = 128; s > 0; s >>= 1) {
        if (threadIdx.x < s) red[threadIdx.x] += red[threadIdx.x + s];
        __syncthreads();
    }
    if (threadIdx.x == 0) { mx[r] = m; sm[r] = red[0]; }
}

// ------------- fused argmax + output gather (one block per label) -------------
__global__ void argmax_gather(
    const float* __restrict__ Zo, const float* __restrict__ Za,
    const float* __restrict__ mxo, const float* __restrict__ smo,
    const float* __restrict__ mxa, const float* __restrict__ sma,
    const int* __restrict__ label_img, const int* __restrict__ num_descs,
    const int* __restrict__ obj_labels, const int* __restrict__ att_labels,
    const int* __restrict__ off, float* __restrict__ out)
{
    const int l = blockIdx.x;
    const int b = label_img[l];
    const int nd = num_descs[b];
    const int r0 = off[b];
    const int t = threadIdx.x;           // 0..255

    __shared__ float ss[128];
    __shared__ int   si[128];
    if (t < 128) {
        float score = -INFINITY;
        if (t < Nq && t < nd) {
            const int r = r0 + t;
            const float po = expf(Zo[(size_t)r * Oq + obj_labels[l]] - mxo[r]) / smo[r];
            const float pa = expf(Za[(size_t)r * Aq + att_labels[l]] - mxa[r]) / sma[r];
            score = po * pa;
        }
        ss[t] = score;
        si[t] = t;
    }
    __syncthreads();
    for (int s = 64; s > 0; s >>= 1) {
        if (t < s) {
            const float s2 = ss[t + s];
            const int   i2 = si[t + s];
            // first-max tie-break; all -inf -> index 0
            if (s2 > ss[t] || (s2 == ss[t] && i2 < si[t])) { ss[t] = s2; si[t] = i2; }
        }
        __syncthreads();
    }
    const int r = r0 + si[0];

    const float mo = mxo[r], so = smo[r];
    const float* zo = Zo + (size_t)r * Oq;
    float* oo = out + (size_t)l * Oq;
    for (int c = t; c < Oq; c += 256)
        oo[c] = expf(zo[c] - mo) / so;

    const float ma = mxa[r], sa = sma[r];
    const float* za = Za + (size_t)r * Aq;
    float* oa = out + (size_t)Lq * Oq + (size_t)l * Aq;
    for (int c = t; c < Aq; c += 256)
        oa[c] = expf(za[c] - ma) / sa;
}

extern "C" void kernel_launch(void* const* d_in, const int* in_sizes, int n_in,
                              void* d_out, int out_size, void* d_ws, size_t ws_size,
                              hipStream_t stream)
{
    const float* x          = (const float*)d_in[0];
    const int*   num_descs  = (const int*)d_in[1];
    const int*   label_img  = (const int*)d_in[2];
    const int*   obj_labels = (const int*)d_in[3];
    const int*   att_labels = (const int*)d_in[4];
    const float* w1o = (const float*)d_in[5];  const float* b1o = (const float*)d_in[6];
    const float* w2o = (const float*)d_in[7];  const float* b2o = (const float*)d_in[8];
    const float* w3o = (const float*)d_in[9];  const float* b3o = (const float*)d_in[10];
    const float* w1a = (const float*)d_in[11]; const float* b1a = (const float*)d_in[12];
    const float* w2a = (const float*)d_in[13]; const float* b2a = (const float*)d_in[14];
    const float* w3a = (const float*)d_in[15]; const float* b3a = (const float*)d_in[16];
    float* out = (float*)d_out;

    // ---- workspace carve with lifetime-based aliasing ----
    char* p = (char*)d_ws;
    auto carve = [&](size_t bytes) { char* q = p; p += (bytes + 255) & ~(size_t)255; return q; };

    char* bufA = carve((size_t)Mq * Dq * 2 * 2);            // xh|xl -> h2{o,a}{h,l}
    char* bufB = carve((size_t)Mq * Hq * 2 * 2 * 2);        // h1{o,a}{h,l} -> z3o|z3a
    ushort* w1oth = (ushort*)carve((size_t)Hq * Dq * 2);  ushort* w1otl = (ushort*)carve((size_t)Hq * Dq * 2);
    ushort* w1ath = (ushort*)carve((size_t)Hq * Dq * 2);  ushort* w1atl = (ushort*)carve((size_t)Hq * Dq * 2);
    ushort* w2oth = (ushort*)carve((size_t)Hq * Hq * 2);  ushort* w2otl = (ushort*)carve((size_t)Hq * Hq * 2);
    ushort* w2ath = (ushort*)carve((size_t)Hq * Hq * 2);  ushort* w2atl = (ushort*)carve((size_t)Hq * Hq * 2);
    ushort* w3oth = (ushort*)carve((size_t)OqP * Hq * 2); ushort* w3otl = (ushort*)carve((size_t)OqP * Hq * 2);
    ushort* w3ath = (ushort*)carve((size_t)AqP * Hq * 2); ushort* w3atl = (ushort*)carve((size_t)AqP * Hq * 2);
    float* mxo = (float*)carve(Mq * 4); float* smo = (float*)carve(Mq * 4);
    float* mxa = (float*)carve(Mq * 4); float* sma = (float*)carve(Mq * 4);
    int* off    = (int*)carve(Bq * 4);
    int* mc     = (int*)carve(2 * 4);
    int* rowmap = (int*)carve(Mq * 4);

    // aliased views
    ushort* xh = (ushort*)bufA;
    ushort* xl = xh + (size_t)Mq * Dq;
    ushort* h2oh = (ushort*)bufA;                    // x dead after L1
    ushort* h2ol = h2oh + (size_t)Mq * Hq;
    ushort* h2ah = h2ol + (size_t)Mq * Hq;
    ushort* h2al = h2ah + (size_t)Mq * Hq;
    ushort* h1oh = (ushort*)bufB;
    ushort* h1ol = h1oh + (size_t)Mq * Hq;
    ushort* h1ah = h1ol + (size_t)Mq * Hq;
    ushort* h1al = h1ah + (size_t)Mq * Hq;
    float* z3o = (float*)bufB;                       // h1 dead after L2
    float* z3a = z3o + (size_t)Mq * Oq;

    // ---- preprocessing ----
    build_offsets<<<1, 128, 0, stream>>>(num_descs, off, mc, rowmap);
    split_compact<<<(int)((size_t)Mq * Dq / 8 / 256), 256, 0, stream>>>(x, rowmap, mc, xh, xl);

    {   // batched weight transpose+split: 6 segments, flat grid
        TSegs ts;
        int base = 0;
        auto seg = [&](const float* W, ushort* Th, ushort* Tl, int K, int N, int Npad) {
            TSeg s; s.W = W; s.Th = Th; s.Tl = Tl; s.K = K; s.N = N;
            s.gx = Npad / 32; s.base = base; base += (Npad / 32) * (K / 32); return s;
        };
        ts.s[0] = seg(w1o, w1oth, w1otl, Dq, Hq, Hq);
        ts.s[1] = seg(w1a, w1ath, w1atl, Dq, Hq, Hq);
        ts.s[2] = seg(w2o, w2oth, w2otl, Hq, Hq, Hq);
        ts.s[3] = seg(w2a, w2ath, w2atl, Hq, Hq, Hq);
        ts.s[4] = seg(w3o, w3oth, w3otl, Hq, Oq, OqP);
        ts.s[5] = seg(w3a, w3ath, w3atl, Hq, Aq, AqP);
        tsplit_all<<<base, 256, 0, stream>>>(ts);
    }

    // ---- L1: h1 = relu(x @ w1 + b1), both branches fused ----
    {
        GArgs go = { xh, xl, w1oth, w1otl, b1o, nullptr, h1oh, h1ol, Dq, Hq, Hq, Dq, Hq, 1 };
        GArgs ga = { xh, xl, w1ath, w1atl, b1a, nullptr, h1ah, h1al, Dq, Hq, Hq, Dq, Hq, 1 };
        gemm_split<<<dim3(Hq / 128, Mq / 128, 2), 256, 0, stream>>>(go, ga, mc);
    }
    // ---- L2: h2 = relu(h1 @ w2 + b2) ----
    {
        GArgs go = { h1oh, h1ol, w2oth, w2otl, b2o, nullptr, h2oh, h2ol, Hq, Hq, Hq, Hq, Hq, 1 };
        GArgs ga = { h1ah, h1al, w2ath, w2atl, b2a, nullptr, h2ah, h2al, Hq, Hq, Hq, Hq, Hq, 1 };
        gemm_split<<<dim3(Hq / 128, Mq / 128, 2), 256, 0, stream>>>(go, ga, mc);
    }
    // ---- L3: z3 = h2 @ w3 + b3 (fp32 out) ----
    {
        GArgs go = { h2oh, h2ol, w3oth, w3otl, b3o, z3o, nullptr, nullptr, Hq, OqP, Oq, Hq, Oq, 0 };
        GArgs ga = { h2ah, h2al, w3ath, w3atl, b3a, z3a, nullptr, nullptr, Hq, AqP, Aq, Hq, Aq, 0 };
        gemm_split<<<dim3(OqP / 128, Mq / 128, 2), 256, 0, stream>>>(go, ga, mc);
    }

    // ---- epilogue ----
    softmax_stats2<<<dim3(Mq, 2), 256, 0, stream>>>(z3o, z3a, mc, mxo, smo, mxa, sma);
    argmax_gather<<<Lq, 256, 0, stream>>>(z3o, z3a, mxo, smo, mxa, sma,
                                          label_img, num_descs, obj_labels, att_labels, off, out);
}

// Round 6
// 704.723 us; speedup vs baseline: 1.2178x; 1.2178x over previous
//
#include <hip/hip_runtime.h>
#include <hip/hip_bf16.h>
#include <math.h>

// Problem constants
#define Bq 128
#define Nq 100
#define Dq 2048
#define Hq 1024
#define Oq 1600
#define Aq 400
#define Lq 2048
#define Mq (Bq * Nq)     // 12800 rows max
#define OqP 1664         // Oq padded to multiple of 128
#define AqP 512          // Aq padded to multiple of 128

typedef __attribute__((ext_vector_type(8))) short bf16x8;
typedef __attribute__((ext_vector_type(16))) float f32x16;
typedef unsigned short ushort;

// Fragment-major layout (for 32x32x16 MFMA operands):
//   chunk index = rowtile(=row/32) * KB + kb(=k/16), KB = K/16
//   within chunk (512 ushort = 1KB): lane' = (row&31) + 32*((k>>3)&1), e = k&7
//   addr = chunk*512 + lane'*8 + e
// A wave ds_read_b128 at chunkbase + lane*16B is the exact MFMA A/B operand
// (lane l: m/n = l&31, k = (l>>5)*8 + e) -- HW-verified in round 4.

// ---------------- helpers ----------------
__device__ __forceinline__ void split1(float v, ushort& h, ushort& l) {
    __hip_bfloat16 bh = __float2bfloat16(v);          // RNE
    float fh = __bfloat162float(bh);
    __hip_bfloat16 bl = __float2bfloat16(v - fh);     // exact residual, then RNE
    h = __builtin_bit_cast(ushort, bh);
    l = __builtin_bit_cast(ushort, bl);
}

__device__ __forceinline__ void gl_lds16(const ushort* g, ushort* lds) {
    __builtin_amdgcn_global_load_lds(
        (const __attribute__((address_space(1))) unsigned int*)g,
        (__attribute__((address_space(3))) unsigned int*)lds,
        16, 0, 0);
}

// ------------- row compaction: offsets + rowmap -------------
__global__ void build_offsets(const int* __restrict__ num_descs,
                              int* __restrict__ off, int* __restrict__ mc,
                              int* __restrict__ rowmap)
{
    __shared__ int cnt[Bq];
    __shared__ int offs[Bq + 1];
    const int t = threadIdx.x;            // 0..127
    int nd = num_descs[t];
    nd = nd < 0 ? 0 : (nd > Nq ? Nq : nd);
    const int c = nd < 1 ? 1 : nd;
    cnt[t] = c;
    __syncthreads();
    if (t == 0) {
        int s = 0;
        for (int i = 0; i < Bq; i++) { offs[i] = s; s += cnt[i]; }
        offs[Bq] = s;
        mc[0] = s;                          // Mc
        mc[1] = (s + 127) & ~127;           // McPad
    }
    __syncthreads();
    off[t] = offs[t];
    for (int i = t; i < Mq; i += Bq) rowmap[i] = -1;
    __syncthreads();
    const int o = offs[t];
    for (int n = 0; n < c; n++) rowmap[o + n] = t * Nq + n;
}

// ------- gather + split x into compact hi/lo bf16, fragment-major -------
__global__ void split_compact(const float* __restrict__ x,
                              const int* __restrict__ rowmap,
                              const int* __restrict__ mc,
                              ushort* __restrict__ hi, ushort* __restrict__ lo)
{
    const long i = ((long)blockIdx.x * blockDim.x + threadIdx.x) * 8;
    const int c = (int)(i >> 11);          // compact row (Dq=2048)
    if (c >= mc[1]) return;
    const int k = (int)(i & 2047);         // 8-aligned
    const int orig = (c < mc[0]) ? rowmap[c] : -1;
    ushort h[8], l[8];
    if (orig < 0) {
#pragma unroll
        for (int j = 0; j < 8; j++) { h[j] = 0; l[j] = 0; }
    } else {
        const float* src = x + (size_t)orig * Dq + k;
        float4 v0 = *(const float4*)(src);
        float4 v1 = *(const float4*)(src + 4);
        float v[8] = {v0.x, v0.y, v0.z, v0.w, v1.x, v1.y, v1.z, v1.w};
#pragma unroll
        for (int j = 0; j < 8; j++) split1(v[j], h[j], l[j]);
    }
    // fragment-major address (KB = Dq/16 = 128)
    const size_t chunk = (size_t)(c >> 5) * (Dq / 16) + (k >> 4);
    const int lanep = (c & 31) + 32 * ((k >> 3) & 1);
    const size_t a = chunk * 512 + (size_t)lanep * 8;
    *(bf16x8*)(hi + a) = *(bf16x8*)h;
    *(bf16x8*)(lo + a) = *(bf16x8*)l;
}

// --- batched transpose+split: W[K][N] -> fragment-major Wt_hi/lo over [Npad][K] ---
struct TSeg { const float* W; ushort* Th; ushort* Tl; int K; int N; int gx; int base; };
struct TSegs { TSeg s[6]; };

__global__ void tsplit_all(TSegs a)
{
    const int id = blockIdx.x;
    TSeg sg = a.s[5];
#pragma unroll
    for (int i = 4; i >= 0; i--) if (id < a.s[i + 1].base) sg = a.s[i];
    const int local = id - sg.base;
    const int bn = (local % sg.gx) * 32;
    const int bk = (local / sg.gx) * 32;
    const int KB = sg.K >> 4;

    __shared__ float t[32][33];
    const int tx = threadIdx.x & 31, ty = threadIdx.x >> 5;   // ty 0..7
#pragma unroll
    for (int i = 0; i < 4; i++) {
        const int k = bk + ty + i * 8, n = bn + tx;
        t[ty + i * 8][tx] = (n < sg.N) ? sg.W[(size_t)k * sg.N + n] : 0.f;
    }
    __syncthreads();
#pragma unroll
    for (int i = 0; i < 4; i++) {
        const int n = bn + ty + i * 8, k = bk + tx;
        const float v = t[tx][ty + i * 8];
        ushort h, l;
        split1(v, h, l);
        const size_t chunk = (size_t)(n >> 5) * KB + (k >> 4);
        const size_t adr = chunk * 512 + (size_t)((n & 31) + 32 * ((k >> 3) & 1)) * 8 + (k & 7);
        sg.Th[adr] = h;
        sg.Tl[adr] = l;
    }
}

// -------- split-bf16 MFMA GEMM: 32x32x16, fragment-major, conflict-free --------
struct GArgs {
    const ushort* Ah; const ushort* Al;     // A fragment-major, K-chunks
    const ushort* Bh; const ushort* Bl;     // B fragment-major (weights, [Npad][K])
    const float* bias;
    float* Cf; ushort* Ch; ushort* Cl;      // outputs
    int K, Npad, Nreal, ldc, mode;          // mode 1: relu+split frag-major; 0: fp32 row-major
};

__global__ __launch_bounds__(256) void gemm_split(GArgs g0, GArgs g1,
                                                  const int* __restrict__ mcp)
{
    const GArgs g = (blockIdx.z == 0) ? g0 : g1;
    const int bm = blockIdx.y * 128;
    const int bn = blockIdx.x * 128;
    if (bn >= g.Npad) return;
    if (bm >= mcp[1]) return;

    const int KB = g.K >> 4;                // chunks along K

    // 4 x 8KB LDS buffers: [rt_local(4)][kb(2)] chunks of 512 ushort
    __shared__ __align__(16) ushort sAh[4096];
    __shared__ __align__(16) ushort sAl[4096];
    __shared__ __align__(16) ushort sBh[4096];
    __shared__ __align__(16) ushort sBl[4096];

    const int tid  = threadIdx.x;
    const int wave = tid >> 6;           // 0..3
    const int lane = tid & 63;
    const int wmi = (wave >> 1) * 2;     // wave's A rowtile base (local, in 32-row units)
    const int wni = (wave & 1) * 2;      // wave's B rowtile base (local)
    const int l31  = lane & 31;
    const int half = lane >> 5;          // 0..1

    // DMA: wave w stages A rowtile (bm/32 + w) and B rowtile (bn/32 + w), kb 0/1, hi+lo
    const ushort* gAh = g.Ah + ((size_t)(bm / 32 + wave) * KB) * 512 + lane * 8;
    const ushort* gAl = g.Al + ((size_t)(bm / 32 + wave) * KB) * 512 + lane * 8;
    const ushort* gBh = g.Bh + ((size_t)(bn / 32 + wave) * KB) * 512 + lane * 8;
    const ushort* gBl = g.Bl + ((size_t)(bn / 32 + wave) * KB) * 512 + lane * 8;
    ushort* lAh = &sAh[wave * 1024];     // 2 chunks per wave slot
    ushort* lAl = &sAl[wave * 1024];
    ushort* lBh = &sBh[wave * 1024];
    ushort* lBl = &sBl[wave * 1024];

    f32x16 acc[2][2] = {};

    for (int kc = 0; kc < KB; kc += 2) {      // 2 chunks (BK=32) per iter
        const size_t go = (size_t)kc * 512;
        gl_lds16(gAh + go, lAh);  gl_lds16(gAh + go + 512, lAh + 512);
        gl_lds16(gAl + go, lAl);  gl_lds16(gAl + go + 512, lAl + 512);
        gl_lds16(gBh + go, lBh);  gl_lds16(gBh + go + 512, lBh + 512);
        gl_lds16(gBl + go, lBl);  gl_lds16(gBl + go + 512, lBl + 512);
        __syncthreads();

#pragma unroll
        for (int ks = 0; ks < 2; ks++) {
            bf16x8 ah[2], al[2], bh[2], bl[2];
#pragma unroll
            for (int i = 0; i < 2; i++) {
                const int sa = ((wmi + i) * 2 + ks) * 512 + lane * 8;
                const int sb = ((wni + i) * 2 + ks) * 512 + lane * 8;
                ah[i] = *(const bf16x8*)&sAh[sa];
                al[i] = *(const bf16x8*)&sAl[sa];
                bh[i] = *(const bf16x8*)&sBh[sb];
                bl[i] = *(const bf16x8*)&sBl[sb];
            }
#pragma unroll
            for (int i = 0; i < 2; i++)
#pragma unroll
                for (int j = 0; j < 2; j++) {
                    acc[i][j] = __builtin_amdgcn_mfma_f32_32x32x16_bf16(ah[i], bh[j], acc[i][j], 0, 0, 0);
                    acc[i][j] = __builtin_amdgcn_mfma_f32_32x32x16_bf16(ah[i], bl[j], acc[i][j], 0, 0, 0);
                    acc[i][j] = __builtin_amdgcn_mfma_f32_32x32x16_bf16(al[i], bh[j], acc[i][j], 0, 0, 0);
                }
        }
        __syncthreads();
    }

    // epilogue: C/D layout col=lane&31, row=(r&3)+8*(r>>2)+4*half (HW-verified r4)
    const int KC = g.ldc >> 4;
#pragma unroll
    for (int j = 0; j < 2; j++) {
        const int col = bn + (wni + j) * 32 + l31;
        if (col < g.Nreal) {
            const float bv = g.bias[col];
#pragma unroll
            for (int i = 0; i < 2; i++) {
#pragma unroll
                for (int r = 0; r < 16; r++) {
                    const int row = bm + (wmi + i) * 32 + (r & 3) + 8 * (r >> 2) + 4 * half;
                    float v = acc[i][j][r] + bv;
                    if (g.mode == 1) {
                        v = fmaxf(v, 0.f);
                        ushort h, l;
                        split1(v, h, l);
                        // fragment-major store for next layer's A
                        const size_t chunk = (size_t)(row >> 5) * KC + (col >> 4);
                        const size_t adr = chunk * 512
                            + (size_t)((row & 31) + 32 * ((col >> 3) & 1)) * 8 + (col & 7);
                        g.Ch[adr] = h;
                        g.Cl[adr] = l;
                    } else {
                        g.Cf[(size_t)row * g.ldc + col] = v;
                    }
                }
            }
        }
    }
}

// ------------- fused per-row softmax stats for both branches -------------
__global__ void softmax_stats2(const float* __restrict__ Zo, const float* __restrict__ Za,
                               const int* __restrict__ mc,
                               float* __restrict__ mxo, float* __restrict__ smo,
                               float* __restrict__ mxa, float* __restrict__ sma)
{
    const int r = blockIdx.x;
    if (r >= mc[0]) return;
    const float* Z; int ncols; float* mx; float* sm;
    if (blockIdx.y == 0) { Z = Zo; ncols = Oq; mx = mxo; sm = smo; }
    else                 { Z = Za; ncols = Aq; mx = mxa; sm = sma; }
    const float* row = Z + (size_t)r * ncols;
    __shared__ float red[256];
    float m = -INFINITY;
    for (int c = threadIdx.x; c < ncols; c += 256) m = fmaxf(m, row[c]);
    red[threadIdx.x] = m;
    __syncthreads();
    for (int s = 128; s > 0; s >>= 1) {
        if (threadIdx.x < s) red[threadIdx.x] = fmaxf(red[threadIdx.x], red[threadIdx.x + s]);
        __syncthreads();
    }
    m = red[0];
    __syncthreads();
    float su = 0.f;
    for (int c = threadIdx.x; c < ncols; c += 256) su += expf(row[c] - m);
    red[threadIdx.x] = su;
    __syncthreads();
    for (int s = 128; s > 0; s >>= 1) {
        if (threadIdx.x < s) red[threadIdx.x] += red[threadIdx.x + s];
        __syncthreads();
    }
    if (threadIdx.x == 0) { mx[r] = m; sm[r] = red[0]; }
}

// ------------- fused argmax + output gather (one block per label) -------------
__global__ void argmax_gather(
    const float* __restrict__ Zo, const float* __restrict__ Za,
    const float* __restrict__ mxo, const float* __restrict__ smo,
    const float* __restrict__ mxa, const float* __restrict__ sma,
    const int* __restrict__ label_img, const int* __restrict__ num_descs,
    const int* __restrict__ obj_labels, const int* __restrict__ att_labels,
    const int* __restrict__ off, float* __restrict__ out)
{
    const int l = blockIdx.x;
    const int b = label_img[l];
    const int nd = num_descs[b];
    const int r0 = off[b];
    const int t = threadIdx.x;           // 0..255

    __shared__ float ss[128];
    __shared__ int   si[128];
    if (t < 128) {
        float score = -INFINITY;
        if (t < Nq && t < nd) {
            const int r = r0 + t;
            const float po = expf(Zo[(size_t)r * Oq + obj_labels[l]] - mxo[r]) / smo[r];
            const float pa = expf(Za[(size_t)r * Aq + att_labels[l]] - mxa[r]) / sma[r];
            score = po * pa;
        }
        ss[t] = score;
        si[t] = t;
    }
    __syncthreads();
    for (int s = 64; s > 0; s >>= 1) {
        if (t < s) {
            const float s2 = ss[t + s];
            const int   i2 = si[t + s];
            // first-max tie-break; all -inf -> index 0
            if (s2 > ss[t] || (s2 == ss[t] && i2 < si[t])) { ss[t] = s2; si[t] = i2; }
        }
        __syncthreads();
    }
    const int r = r0 + si[0];

    const float mo = mxo[r], so = smo[r];
    const float* zo = Zo + (size_t)r * Oq;
    float* oo = out + (size_t)l * Oq;
    for (int c = t; c < Oq; c += 256)
        oo[c] = expf(zo[c] - mo) / so;

    const float ma = mxa[r], sa = sma[r];
    const float* za = Za + (size_t)r * Aq;
    float* oa = out + (size_t)Lq * Oq + (size_t)l * Aq;
    for (int c = t; c < Aq; c += 256)
        oa[c] = expf(za[c] - ma) / sa;
}

extern "C" void kernel_launch(void* const* d_in, const int* in_sizes, int n_in,
                              void* d_out, int out_size, void* d_ws, size_t ws_size,
                              hipStream_t stream)
{
    const float* x          = (const float*)d_in[0];
    const int*   num_descs  = (const int*)d_in[1];
    const int*   label_img  = (const int*)d_in[2];
    const int*   obj_labels = (const int*)d_in[3];
    const int*   att_labels = (const int*)d_in[4];
    const float* w1o = (const float*)d_in[5];  const float* b1o = (const float*)d_in[6];
    const float* w2o = (const float*)d_in[7];  const float* b2o = (const float*)d_in[8];
    const float* w3o = (const float*)d_in[9];  const float* b3o = (const float*)d_in[10];
    const float* w1a = (const float*)d_in[11]; const float* b1a = (const float*)d_in[12];
    const float* w2a = (const float*)d_in[13]; const float* b2a = (const float*)d_in[14];
    const float* w3a = (const float*)d_in[15]; const float* b3a = (const float*)d_in[16];
    float* out = (float*)d_out;

    // ---- workspace carve with lifetime-based aliasing ----
    char* p = (char*)d_ws;
    auto carve = [&](size_t bytes) { char* q = p; p += (bytes + 255) & ~(size_t)255; return q; };

    char* bufA = carve((size_t)Mq * Dq * 2 * 2);            // xh|xl -> h2{o,a}{h,l}
    char* bufB = carve((size_t)Mq * Hq * 2 * 2 * 2);        // h1{o,a}{h,l} -> z3o|z3a
    ushort* w1oth = (ushort*)carve((size_t)Hq * Dq * 2);  ushort* w1otl = (ushort*)carve((size_t)Hq * Dq * 2);
    ushort* w1ath = (ushort*)carve((size_t)Hq * Dq * 2);  ushort* w1atl = (ushort*)carve((size_t)Hq * Dq * 2);
    ushort* w2oth = (ushort*)carve((size_t)Hq * Hq * 2);  ushort* w2otl = (ushort*)carve((size_t)Hq * Hq * 2);
    ushort* w2ath = (ushort*)carve((size_t)Hq * Hq * 2);  ushort* w2atl = (ushort*)carve((size_t)Hq * Hq * 2);
    ushort* w3oth = (ushort*)carve((size_t)OqP * Hq * 2); ushort* w3otl = (ushort*)carve((size_t)OqP * Hq * 2);
    ushort* w3ath = (ushort*)carve((size_t)AqP * Hq * 2); ushort* w3atl = (ushort*)carve((size_t)AqP * Hq * 2);
    float* mxo = (float*)carve(Mq * 4); float* smo = (float*)carve(Mq * 4);
    float* mxa = (float*)carve(Mq * 4); float* sma = (float*)carve(Mq * 4);
    int* off    = (int*)carve(Bq * 4);
    int* mc     = (int*)carve(2 * 4);
    int* rowmap = (int*)carve(Mq * 4);

    // aliased views
    ushort* xh = (ushort*)bufA;
    ushort* xl = xh + (size_t)Mq * Dq;
    ushort* h2oh = (ushort*)bufA;                    // x dead after L1
    ushort* h2ol = h2oh + (size_t)Mq * Hq;
    ushort* h2ah = h2ol + (size_t)Mq * Hq;
    ushort* h2al = h2ah + (size_t)Mq * Hq;
    ushort* h1oh = (ushort*)bufB;
    ushort* h1ol = h1oh + (size_t)Mq * Hq;
    ushort* h1ah = h1ol + (size_t)Mq * Hq;
    ushort* h1al = h1ah + (size_t)Mq * Hq;
    float* z3o = (float*)bufB;                       // h1 dead after L2
    float* z3a = z3o + (size_t)Mq * Oq;

    // ---- preprocessing ----
    build_offsets<<<1, 128, 0, stream>>>(num_descs, off, mc, rowmap);
    split_compact<<<(int)((size_t)Mq * Dq / 8 / 256), 256, 0, stream>>>(x, rowmap, mc, xh, xl);

    {   // batched weight transpose+split (fragment-major): 6 segments, flat grid
        TSegs ts;
        int base = 0;
        auto seg = [&](const float* W, ushort* Th, ushort* Tl, int K, int N, int Npad) {
            TSeg s; s.W = W; s.Th = Th; s.Tl = Tl; s.K = K; s.N = N;
            s.gx = Npad / 32; s.base = base; base += (Npad / 32) * (K / 32); return s;
        };
        ts.s[0] = seg(w1o, w1oth, w1otl, Dq, Hq, Hq);
        ts.s[1] = seg(w1a, w1ath, w1atl, Dq, Hq, Hq);
        ts.s[2] = seg(w2o, w2oth, w2otl, Hq, Hq, Hq);
        ts.s[3] = seg(w2a, w2ath, w2atl, Hq, Hq, Hq);
        ts.s[4] = seg(w3o, w3oth, w3otl, Hq, Oq, OqP);
        ts.s[5] = seg(w3a, w3ath, w3atl, Hq, Aq, AqP);
        tsplit_all<<<base, 256, 0, stream>>>(ts);
    }

    // ---- L1: h1 = relu(x @ w1 + b1), both branches fused ----
    {
        GArgs go = { xh, xl, w1oth, w1otl, b1o, nullptr, h1oh, h1ol, Dq, Hq, Hq, Hq, 1 };
        GArgs ga = { xh, xl, w1ath, w1atl, b1a, nullptr, h1ah, h1al, Dq, Hq, Hq, Hq, 1 };
        gemm_split<<<dim3(Hq / 128, Mq / 128, 2), 256, 0, stream>>>(go, ga, mc);
    }
    // ---- L2: h2 = relu(h1 @ w2 + b2) ----
    {
        GArgs go = { h1oh, h1ol, w2oth, w2otl, b2o, nullptr, h2oh, h2ol, Hq, Hq, Hq, Hq, 1 };
        GArgs ga = { h1ah, h1al, w2ath, w2atl, b2a, nullptr, h2ah, h2al, Hq, Hq, Hq, Hq, 1 };
        gemm_split<<<dim3(Hq / 128, Mq / 128, 2), 256, 0, stream>>>(go, ga, mc);
    }
    // ---- L3: z3 = h2 @ w3 + b3 (fp32 row-major out) ----
    {
        GArgs go = { h2oh, h2ol, w3oth, w3otl, b3o, z3o, nullptr, nullptr, Hq, OqP, Oq, Oq, 0 };
        GArgs ga = { h2ah, h2al, w3ath, w3atl, b3a, z3a, nullptr, nullptr, Hq, AqP, Aq, Aq, 0 };
        gemm_split<<<dim3(OqP / 128, Mq / 128, 2), 256, 0, stream>>>(go, ga, mc);
    }

    // ---- epilogue ----
    softmax_stats2<<<dim3(Mq, 2), 256, 0, stream>>>(z3o, z3a, mc, mxo, smo, mxa, sma);
    argmax_gather<<<Lq, 256, 0, stream>>>(z3o, z3a, mxo, smo, mxa, sma,
                                          label_img, num_descs, obj_labels, att_labels, off, out);
}

// Round 7
// 675.317 us; speedup vs baseline: 1.2708x; 1.0435x over previous
//
#include <hip/hip_runtime.h>
#include <hip/hip_bf16.h>
#include <math.h>

// Problem constants
#define Bq 128
#define Nq 100
#define Dq 2048
#define Hq 1024
#define Oq 1600
#define Aq 400
#define Lq 2048
#define Mq (Bq * Nq)     // 12800 rows max
#define OqP 1664         // Oq padded to multiple of 128
#define AqP 512          // Aq padded to multiple of 128

typedef __attribute__((ext_vector_type(8))) short bf16x8;
typedef __attribute__((ext_vector_type(16))) float f32x16;
typedef unsigned short ushort;

// Fragment-major layout (32x32x16 MFMA operands):
//   chunk = rowtile(row/32) * KB + kb(k/16), KB = K/16
//   lane' = (row&31) + 32*((k>>3)&1), elem = k&7
//   addr  = chunk*512 + lane'*8 + elem
// One wave ds_read_b128/global-store at chunkbase + lane*16B == exact MFMA operand.

// ---------------- helpers ----------------
__device__ __forceinline__ void split1(float v, ushort& h, ushort& l) {
    __hip_bfloat16 bh = __float2bfloat16(v);          // RNE
    float fh = __bfloat162float(bh);
    __hip_bfloat16 bl = __float2bfloat16(v - fh);     // exact residual, then RNE
    h = __builtin_bit_cast(ushort, bh);
    l = __builtin_bit_cast(ushort, bl);
}

__device__ __forceinline__ void gl_lds16(const ushort* g, ushort* lds) {
    __builtin_amdgcn_global_load_lds(
        (const __attribute__((address_space(1))) unsigned int*)g,
        (__attribute__((address_space(3))) unsigned int*)lds,
        16, 0, 0);
}

// ------------- row compaction: offsets + rowmap -------------
__global__ void build_offsets(const int* __restrict__ num_descs,
                              int* __restrict__ off, int* __restrict__ mc,
                              int* __restrict__ rowmap)
{
    __shared__ int cnt[Bq];
    __shared__ int offs[Bq + 1];
    const int t = threadIdx.x;            // 0..127
    int nd = num_descs[t];
    nd = nd < 0 ? 0 : (nd > Nq ? Nq : nd);
    const int c = nd < 1 ? 1 : nd;
    cnt[t] = c;
    __syncthreads();
    if (t == 0) {
        int s = 0;
        for (int i = 0; i < Bq; i++) { offs[i] = s; s += cnt[i]; }
        offs[Bq] = s;
        mc[0] = s;                          // Mc
        mc[1] = (s + 127) & ~127;           // McPad
    }
    __syncthreads();
    off[t] = offs[t];
    for (int i = t; i < Mq; i += Bq) rowmap[i] = -1;
    __syncthreads();
    const int o = offs[t];
    for (int n = 0; n < c; n++) rowmap[o + n] = t * Nq + n;
}

// -- gather + split x into compact hi/lo bf16, fragment-major, wave-per-chunk --
// lane: row = rt*32 + (lane&31), k = kb*16 + (lane>>5)*8; both chunk stores
// land at chunkbase + lane*16B -> fully coalesced 1KB wave stores.
__global__ void split_compact(const float* __restrict__ x,
                              const int* __restrict__ rowmap,
                              const int* __restrict__ mc,
                              ushort* __restrict__ hi, ushort* __restrict__ lo)
{
    const int KB = Dq / 16;   // 128
    const int wid = (blockIdx.x * blockDim.x + threadIdx.x) >> 6;   // chunk id
    const int lane = threadIdx.x & 63;
    const int rt = wid / KB;
    const int kb = wid - rt * KB;
    if (rt * 32 >= mc[1]) return;
    const int crow = rt * 32 + (lane & 31);
    const int k = kb * 16 + (lane >> 5) * 8;
    const int orig = (crow < mc[0]) ? rowmap[crow] : -1;
    ushort h[8], l[8];
    if (orig < 0) {
#pragma unroll
        for (int j = 0; j < 8; j++) { h[j] = 0; l[j] = 0; }
    } else {
        const float* src = x + (size_t)orig * Dq + k;
        float4 v0 = *(const float4*)(src);
        float4 v1 = *(const float4*)(src + 4);
        float v[8] = {v0.x, v0.y, v0.z, v0.w, v1.x, v1.y, v1.z, v1.w};
#pragma unroll
        for (int j = 0; j < 8; j++) split1(v[j], h[j], l[j]);
    }
    const size_t a = (size_t)wid * 512 + (size_t)lane * 8;
    *(bf16x8*)(hi + a) = *(bf16x8*)h;
    *(bf16x8*)(lo + a) = *(bf16x8*)l;
}

// --- batched transpose+split: W[K][N] -> fragment-major Wt_hi/lo over [Npad][K] ---
// Block: 32n x 32k tile. Load coalesced -> LDS. Write: wave w produces chunk
// (k-half = w&1) of (hi if w<2 else lo) with one coalesced 1KB store.
struct TSeg { const float* W; ushort* Th; ushort* Tl; int K; int N; int gx; int base; };
struct TSegs { TSeg s[6]; };

__global__ void tsplit_all(TSegs a)
{
    const int id = blockIdx.x;
    TSeg sg = a.s[5];
#pragma unroll
    for (int i = 4; i >= 0; i--) if (id < a.s[i + 1].base) sg = a.s[i];
    const int local = id - sg.base;
    const int bn = (local % sg.gx) * 32;
    const int bk = (local / sg.gx) * 32;
    const int KB = sg.K >> 4;

    __shared__ float t[32][33];   // t[k][n]
    const int tx = threadIdx.x & 31, ty = threadIdx.x >> 5;   // ty 0..7
#pragma unroll
    for (int i = 0; i < 4; i++) {
        const int k = bk + ty + i * 8, n = bn + tx;
        t[ty + i * 8][tx] = (n < sg.N) ? sg.W[(size_t)k * sg.N + n] : 0.f;
    }
    __syncthreads();

    // write phase: 4 waves; wave = (hl<<1)|kc ; lane covers (n&31, k-half)
    const int wave = threadIdx.x >> 6;
    const int lane = threadIdx.x & 63;
    const int kc = wave & 1;            // which 16-k chunk of the 32k tile
    const int hl = wave >> 1;           // 0 = hi, 1 = lo
    const int nloc = lane & 31;
    const int kloc = kc * 16 + (lane >> 5) * 8;
    ushort v8[8];
#pragma unroll
    for (int e = 0; e < 8; e++) {
        ushort h, l;
        split1(t[kloc + e][nloc], h, l);
        v8[e] = hl ? l : h;
    }
    const size_t chunk = (size_t)((bn >> 5)) * KB + (bk >> 4) + kc;
    ushort* dst = (hl ? sg.Tl : sg.Th) + chunk * 512 + (size_t)lane * 8;
    *(bf16x8*)dst = *(bf16x8*)v8;
}

// -------- split-bf16 MFMA GEMM: 32x32x16, fragment-major, conflict-free --------
struct GArgs {
    const ushort* Ah; const ushort* Al;     // A fragment-major, K-chunks
    const ushort* Bh; const ushort* Bl;     // B fragment-major (weights, [Npad][K])
    const float* bias;
    float* Cf; ushort* Ch; ushort* Cl;      // outputs
    int K, Npad, Nreal, ldc, mode;          // mode 1: relu+split frag-major; 0: fp32 row-major
};

__global__ __launch_bounds__(256) void gemm_split(GArgs g0, GArgs g1,
                                                  const int* __restrict__ mcp)
{
    const GArgs g = (blockIdx.z == 0) ? g0 : g1;
    const int bm = blockIdx.y * 128;
    const int bn = blockIdx.x * 128;
    if (bn >= g.Npad) return;
    if (bm >= mcp[1]) return;

    const int KB = g.K >> 4;                // chunks along K

    __shared__ __align__(16) ushort sAh[4096];
    __shared__ __align__(16) ushort sAl[4096];
    __shared__ __align__(16) ushort sBh[4096];
    __shared__ __align__(16) ushort sBl[4096];

    const int tid  = threadIdx.x;
    const int wave = tid >> 6;           // 0..3
    const int lane = tid & 63;
    const int wmi = (wave >> 1) * 2;     // wave's A rowtile base (local, 32-row units)
    const int wni = (wave & 1) * 2;      // wave's B rowtile base (local)
    const int l31  = lane & 31;
    const int half = lane >> 5;          // 0..1

    const ushort* gAh = g.Ah + ((size_t)(bm / 32 + wave) * KB) * 512 + lane * 8;
    const ushort* gAl = g.Al + ((size_t)(bm / 32 + wave) * KB) * 512 + lane * 8;
    const ushort* gBh = g.Bh + ((size_t)(bn / 32 + wave) * KB) * 512 + lane * 8;
    const ushort* gBl = g.Bl + ((size_t)(bn / 32 + wave) * KB) * 512 + lane * 8;
    ushort* lAh = &sAh[wave * 1024];
    ushort* lAl = &sAl[wave * 1024];
    ushort* lBh = &sBh[wave * 1024];
    ushort* lBl = &sBl[wave * 1024];

    f32x16 acc[2][2] = {};

    for (int kc = 0; kc < KB; kc += 2) {      // 2 chunks (BK=32) per iter
        const size_t go = (size_t)kc * 512;
        gl_lds16(gAh + go, lAh);  gl_lds16(gAh + go + 512, lAh + 512);
        gl_lds16(gAl + go, lAl);  gl_lds16(gAl + go + 512, lAl + 512);
        gl_lds16(gBh + go, lBh);  gl_lds16(gBh + go + 512, lBh + 512);
        gl_lds16(gBl + go, lBl);  gl_lds16(gBl + go + 512, lBl + 512);
        __syncthreads();

#pragma unroll
        for (int ks = 0; ks < 2; ks++) {
            bf16x8 ah[2], al[2], bh[2], bl[2];
#pragma unroll
            for (int i = 0; i < 2; i++) {
                const int sa = ((wmi + i) * 2 + ks) * 512 + lane * 8;
                const int sb = ((wni + i) * 2 + ks) * 512 + lane * 8;
                ah[i] = *(const bf16x8*)&sAh[sa];
                al[i] = *(const bf16x8*)&sAl[sa];
                bh[i] = *(const bf16x8*)&sBh[sb];
                bl[i] = *(const bf16x8*)&sBl[sb];
            }
#pragma unroll
            for (int i = 0; i < 2; i++)
#pragma unroll
                for (int j = 0; j < 2; j++) {
                    acc[i][j] = __builtin_amdgcn_mfma_f32_32x32x16_bf16(ah[i], bh[j], acc[i][j], 0, 0, 0);
                    acc[i][j] = __builtin_amdgcn_mfma_f32_32x32x16_bf16(ah[i], bl[j], acc[i][j], 0, 0, 0);
                    acc[i][j] = __builtin_amdgcn_mfma_f32_32x32x16_bf16(al[i], bh[j], acc[i][j], 0, 0, 0);
                }
        }
        __syncthreads();
    }

    // epilogue: C/D layout col=lane&31, row=(r&3)+8*(r>>2)+4*half (HW-verified r4)
    const int KC = g.ldc >> 4;
#pragma unroll
    for (int j = 0; j < 2; j++) {
        const int col = bn + (wni + j) * 32 + l31;
        if (col < g.Nreal) {
            const float bv = g.bias[col];
#pragma unroll
            for (int i = 0; i < 2; i++) {
#pragma unroll
                for (int r = 0; r < 16; r++) {
                    const int row = bm + (wmi + i) * 32 + (r & 3) + 8 * (r >> 2) + 4 * half;
                    float v = acc[i][j][r] + bv;
                    if (g.mode == 1) {
                        v = fmaxf(v, 0.f);
                        ushort h, l;
                        split1(v, h, l);
                        const size_t chunk = (size_t)(row >> 5) * KC + (col >> 4);
                        const size_t adr = chunk * 512
                            + (size_t)((row & 31) + 32 * ((col >> 3) & 1)) * 8 + (col & 7);
                        g.Ch[adr] = h;
                        g.Cl[adr] = l;
                    } else {
                        g.Cf[(size_t)row * g.ldc + col] = v;
                    }
                }
            }
        }
    }
}

// ------------- fused per-row softmax stats for both branches -------------
__global__ void softmax_stats2(const float* __restrict__ Zo, const float* __restrict__ Za,
                               const int* __restrict__ mc,
                               float* __restrict__ mxo, float* __restrict__ smo,
                               float* __restrict__ mxa, float* __restrict__ sma)
{
    const int r = blockIdx.x;
    if (r >= mc[0]) return;
    const float* Z; int ncols; float* mx; float* sm;
    if (blockIdx.y == 0) { Z = Zo; ncols = Oq; mx = mxo; sm = smo; }
    else                 { Z = Za; ncols = Aq; mx = mxa; sm = sma; }
    const float* row = Z + (size_t)r * ncols;
    __shared__ float red[256];
    float m = -INFINITY;
    for (int c = threadIdx.x; c < ncols; c += 256) m = fmaxf(m, row[c]);
    red[threadIdx.x] = m;
    __syncthreads();
    for (int s = 128; s > 0; s >>= 1) {
        if (threadIdx.x < s) red[threadIdx.x] = fmaxf(red[threadIdx.x], red[threadIdx.x + s]);
        __syncthreads();
    }
    m = red[0];
    __syncthreads();
    float su = 0.f;
    for (int c = threadIdx.x; c < ncols; c += 256) su += expf(row[c] - m);
    red[threadIdx.x] = su;
    __syncthreads();
    for (int s = 128; s > 0; s >>= 1) {
        if (threadIdx.x < s) red[threadIdx.x] += red[threadIdx.x + s];
        __syncthreads();
    }
    if (threadIdx.x == 0) { mx[r] = m; sm[r] = red[0]; }
}

// ------------- fused argmax + output gather (one block per label) -------------
__global__ void argmax_gather(
    const float* __restrict__ Zo, const float* __restrict__ Za,
    const float* __restrict__ mxo, const float* __restrict__ smo,
    const float* __restrict__ mxa, const float* __restrict__ sma,
    const int* __restrict__ label_img, const int* __restrict__ num_descs,
    const int* __restrict__ obj_labels, const int* __restrict__ att_labels,
    const int* __restrict__ off, float* __restrict__ out)
{
    const int l = blockIdx.x;
    const int b = label_img[l];
    const int nd = num_descs[b];
    const int r0 = off[b];
    const int t = threadIdx.x;           // 0..255

    __shared__ float ss[128];
    __shared__ int   si[128];
    if (t < 128) {
        float score = -INFINITY;
        if (t < Nq && t < nd) {
            const int r = r0 + t;
            const float po = expf(Zo[(size_t)r * Oq + obj_labels[l]] - mxo[r]) / smo[r];
            const float pa = expf(Za[(size_t)r * Aq + att_labels[l]] - mxa[r]) / sma[r];
            score = po * pa;
        }
        ss[t] = score;
        si[t] = t;
    }
    __syncthreads();
    for (int s = 64; s > 0; s >>= 1) {
        if (t < s) {
            const float s2 = ss[t + s];
            const int   i2 = si[t + s];
            // first-max tie-break; all -inf -> index 0
            if (s2 > ss[t] || (s2 == ss[t] && i2 < si[t])) { ss[t] = s2; si[t] = i2; }
        }
        __syncthreads();
    }
    const int r = r0 + si[0];

    const float mo = mxo[r], so = smo[r];
    const float* zo = Zo + (size_t)r * Oq;
    float* oo = out + (size_t)l * Oq;
    for (int c = t; c < Oq; c += 256)
        oo[c] = expf(zo[c] - mo) / so;

    const float ma = mxa[r], sa = sma[r];
    const float* za = Za + (size_t)r * Aq;
    float* oa = out + (size_t)Lq * Oq + (size_t)l * Aq;
    for (int c = t; c < Aq; c += 256)
        oa[c] = expf(za[c] - ma) / sa;
}

extern "C" void kernel_launch(void* const* d_in, const int* in_sizes, int n_in,
                              void* d_out, int out_size, void* d_ws, size_t ws_size,
                              hipStream_t stream)
{
    const float* x          = (const float*)d_in[0];
    const int*   num_descs  = (const int*)d_in[1];
    const int*   label_img  = (const int*)d_in[2];
    const int*   obj_labels = (const int*)d_in[3];
    const int*   att_labels = (const int*)d_in[4];
    const float* w1o = (const float*)d_in[5];  const float* b1o = (const float*)d_in[6];
    const float* w2o = (const float*)d_in[7];  const float* b2o = (const float*)d_in[8];
    const float* w3o = (const float*)d_in[9];  const float* b3o = (const float*)d_in[10];
    const float* w1a = (const float*)d_in[11]; const float* b1a = (const float*)d_in[12];
    const float* w2a = (const float*)d_in[13]; const float* b2a = (const float*)d_in[14];
    const float* w3a = (const float*)d_in[15]; const float* b3a = (const float*)d_in[16];
    float* out = (float*)d_out;

    // ---- workspace carve with lifetime-based aliasing ----
    char* p = (char*)d_ws;
    auto carve = [&](size_t bytes) { char* q = p; p += (bytes + 255) & ~(size_t)255; return q; };

    char* bufA = carve((size_t)Mq * Dq * 2 * 2);            // xh|xl -> h2{o,a}{h,l}
    char* bufB = carve((size_t)Mq * Hq * 2 * 2 * 2);        // h1{o,a}{h,l} -> z3o|z3a
    ushort* w1oth = (ushort*)carve((size_t)Hq * Dq * 2);  ushort* w1otl = (ushort*)carve((size_t)Hq * Dq * 2);
    ushort* w1ath = (ushort*)carve((size_t)Hq * Dq * 2);  ushort* w1atl = (ushort*)carve((size_t)Hq * Dq * 2);
    ushort* w2oth = (ushort*)carve((size_t)Hq * Hq * 2);  ushort* w2otl = (ushort*)carve((size_t)Hq * Hq * 2);
    ushort* w2ath = (ushort*)carve((size_t)Hq * Hq * 2);  ushort* w2atl = (ushort*)carve((size_t)Hq * Hq * 2);
    ushort* w3oth = (ushort*)carve((size_t)OqP * Hq * 2); ushort* w3otl = (ushort*)carve((size_t)OqP * Hq * 2);
    ushort* w3ath = (ushort*)carve((size_t)AqP * Hq * 2); ushort* w3atl = (ushort*)carve((size_t)AqP * Hq * 2);
    float* mxo = (float*)carve(Mq * 4); float* smo = (float*)carve(Mq * 4);
    float* mxa = (float*)carve(Mq * 4); float* sma = (float*)carve(Mq * 4);
    int* off    = (int*)carve(Bq * 4);
    int* mc     = (int*)carve(2 * 4);
    int* rowmap = (int*)carve(Mq * 4);

    // aliased views
    ushort* xh = (ushort*)bufA;
    ushort* xl = xh + (size_t)Mq * Dq;
    ushort* h2oh = (ushort*)bufA;                    // x dead after L1
    ushort* h2ol = h2oh + (size_t)Mq * Hq;
    ushort* h2ah = h2ol + (size_t)Mq * Hq;
    ushort* h2al = h2ah + (size_t)Mq * Hq;
    ushort* h1oh = (ushort*)bufB;
    ushort* h1ol = h1oh + (size_t)Mq * Hq;
    ushort* h1ah = h1ol + (size_t)Mq * Hq;
    ushort* h1al = h1ah + (size_t)Mq * Hq;
    float* z3o = (float*)bufB;                       // h1 dead after L2
    float* z3a = z3o + (size_t)Mq * Oq;

    // ---- preprocessing ----
    build_offsets<<<1, 128, 0, stream>>>(num_descs, off, mc, rowmap);
    // wave-per-chunk: (Mq/32)*(Dq/16) waves, 4 waves/block
    split_compact<<<(Mq / 32) * (Dq / 16) / 4, 256, 0, stream>>>(x, rowmap, mc, xh, xl);

    {   // batched weight transpose+split (fragment-major): 6 segments, flat grid
        TSegs ts;
        int base = 0;
        auto seg = [&](const float* W, ushort* Th, ushort* Tl, int K, int N, int Npad) {
            TSeg s; s.W = W; s.Th = Th; s.Tl = Tl; s.K = K; s.N = N;
            s.gx = Npad / 32; s.base = base; base += (Npad / 32) * (K / 32); return s;
        };
        ts.s[0] = seg(w1o, w1oth, w1otl, Dq, Hq, Hq);
        ts.s[1] = seg(w1a, w1ath, w1atl, Dq, Hq, Hq);
        ts.s[2] = seg(w2o, w2oth, w2otl, Hq, Hq, Hq);
        ts.s[3] = seg(w2a, w2ath, w2atl, Hq, Hq, Hq);
        ts.s[4] = seg(w3o, w3oth, w3otl, Hq, Oq, OqP);
        ts.s[5] = seg(w3a, w3ath, w3atl, Hq, Aq, AqP);
        tsplit_all<<<base, 256, 0, stream>>>(ts);
    }

    // ---- L1: h1 = relu(x @ w1 + b1), both branches fused ----
    {
        GArgs go = { xh, xl, w1oth, w1otl, b1o, nullptr, h1oh, h1ol, Dq, Hq, Hq, Hq, 1 };
        GArgs ga = { xh, xl, w1ath, w1atl, b1a, nullptr, h1ah, h1al, Dq, Hq, Hq, Hq, 1 };
        gemm_split<<<dim3(Hq / 128, Mq / 128, 2), 256, 0, stream>>>(go, ga, mc);
    }
    // ---- L2: h2 = relu(h1 @ w2 + b2) ----
    {
        GArgs go = { h1oh, h1ol, w2oth, w2otl, b2o, nullptr, h2oh, h2ol, Hq, Hq, Hq, Hq, 1 };
        GArgs ga = { h1ah, h1al, w2ath, w2atl, b2a, nullptr, h2ah, h2al, Hq, Hq, Hq, Hq, 1 };
        gemm_split<<<dim3(Hq / 128, Mq / 128, 2), 256, 0, stream>>>(go, ga, mc);
    }
    // ---- L3: z3 = h2 @ w3 + b3 (fp32 row-major out) ----
    {
        GArgs go = { h2oh, h2ol, w3oth, w3otl, b3o, z3o, nullptr, nullptr, Hq, OqP, Oq, Oq, 0 };
        GArgs ga = { h2ah, h2al, w3ath, w3atl, b3a, z3a, nullptr, nullptr, Hq, AqP, Aq, Aq, 0 };
        gemm_split<<<dim3(OqP / 128, Mq / 128, 2), 256, 0, stream>>>(go, ga, mc);
    }

    // ---- epilogue ----
    softmax_stats2<<<dim3(Mq, 2), 256, 0, stream>>>(z3o, z3a, mc, mxo, smo, mxa, sma);
    argmax_gather<<<Lq, 256, 0, stream>>>(z3o, z3a, mxo, smo, mxa, sma,
                                          label_img, num_descs, obj_labels, att_labels, off, out);
}